// Round 12
// baseline (1058.313 us; speedup 1.0000x reference)
//
#include <hip/hip_runtime.h>

#define NN 100000
#define EE 400000
#define HH 512
#define NB_SCAN 98   // ceil(NN/1024)

typedef __attribute__((ext_vector_type(8))) short short8;
typedef __attribute__((ext_vector_type(8))) unsigned short ushort8;
typedef __attribute__((ext_vector_type(4))) float f32x4;

__device__ inline unsigned short f2b(float f) {   // f32 -> bf16 RNE
    unsigned int u = __float_as_uint(f);
    return (unsigned short)((u + 0x7fffu + ((u >> 16) & 1u)) >> 16);
}
__device__ inline float b2f(unsigned short b) {
    return __uint_as_float(((unsigned int)b) << 16);
}

// ================= CSR build =================
__global__ void histo_deg(const int* __restrict__ dst, int* __restrict__ deg) {
    int e = blockIdx.x * blockDim.x + threadIdx.x;
    if (e < EE) atomicAdd(&deg[dst[e]], 1);
}

__global__ void scan_reduce(const int* __restrict__ deg, int* __restrict__ blockSums) {
    __shared__ int s[256];
    int b = blockIdx.x, t = threadIdx.x;
    int base = b * 1024 + t * 4;
    int v = 0;
    #pragma unroll
    for (int j = 0; j < 4; ++j) { int i = base + j; if (i < NN) v += deg[i]; }
    s[t] = v; __syncthreads();
    for (int off = 128; off > 0; off >>= 1) {
        if (t < off) s[t] += s[t + off];
        __syncthreads();
    }
    if (t == 0) blockSums[b] = s[0];
}

__global__ void scan_top(int* __restrict__ blockSums, int* __restrict__ start) {
    __shared__ int s[128];
    int t = threadIdx.x;
    s[t] = (t < NB_SCAN) ? blockSums[t] : 0;
    __syncthreads();
    for (int off = 1; off < 128; off <<= 1) {
        int u = (t >= off) ? s[t - off] : 0;
        __syncthreads();
        s[t] += u;
        __syncthreads();
    }
    if (t < NB_SCAN) blockSums[t] = (t == 0) ? 0 : s[t - 1];  // exclusive
    if (t == 0) start[NN] = EE;
}

__global__ void scan_down(const int* __restrict__ deg, const int* __restrict__ blockSums,
                          int* __restrict__ start, int* __restrict__ cursor) {
    __shared__ int s[256];
    int b = blockIdx.x, t = threadIdx.x;
    int base = b * 1024 + t * 4;
    int v[4]; int sum = 0;
    #pragma unroll
    for (int j = 0; j < 4; ++j) {
        int i = base + j;
        v[j] = (i < NN) ? deg[i] : 0;
        sum += v[j];
    }
    s[t] = sum; __syncthreads();
    for (int off = 1; off < 256; off <<= 1) {
        int u = (t >= off) ? s[t - off] : 0;
        __syncthreads();
        s[t] += u;
        __syncthreads();
    }
    int excl = blockSums[b] + ((t == 0) ? 0 : s[t - 1]);
    #pragma unroll
    for (int j = 0; j < 4; ++j) {
        int i = base + j;
        if (i < NN) { start[i] = excl; cursor[i] = excl; excl += v[j]; }
    }
}

__global__ void csr_fill(const int* __restrict__ src, const int* __restrict__ dst,
                         int* __restrict__ cursor, int* __restrict__ eidx) {
    int e = blockIdx.x * blockDim.x + threadIdx.x;
    if (e < EE) {
        int p = atomicAdd(&cursor[dst[e]], 1);
        eidx[p] = src[e];
    }
}

// ================= Weight transpose + bf16 convert =================
__global__ void w_transpose(const float* __restrict__ w, unsigned short* __restrict__ wt) {
    int idx = blockIdx.x * 256 + threadIdx.x;  // n*512 + k, k fastest
    int n = idx >> 9, k = idx & 511;
    wt[idx] = f2b(w[(size_t)k * HH + n]);
}

// ================= Aggregation: bf16 gather, one wave per node =================
// 4-deep software pipeline: issue 4 independent row loads per iteration (MLP).
__global__ __launch_bounds__(256) void gather_rows_b(
    const unsigned short* __restrict__ xb, const int* __restrict__ start,
    const int* __restrict__ eidx, unsigned short* __restrict__ agg)
{
    int node = blockIdx.x * 4 + (threadIdx.x >> 6);
    if (node >= NN) return;
    int c0 = (threadIdx.x & 63) << 3;   // 8 bf16 per lane
    float a[8] = {0.f,0.f,0.f,0.f,0.f,0.f,0.f,0.f};
    int e0 = start[node], e1 = start[node + 1];
    int e = e0;
    for (; e + 4 <= e1; e += 4) {
        int s0 = eidx[e], s1 = eidx[e + 1], s2 = eidx[e + 2], s3 = eidx[e + 3];
        ushort8 v0 = *(const ushort8*)(xb + (size_t)s0 * HH + c0);
        ushort8 v1 = *(const ushort8*)(xb + (size_t)s1 * HH + c0);
        ushort8 v2 = *(const ushort8*)(xb + (size_t)s2 * HH + c0);
        ushort8 v3 = *(const ushort8*)(xb + (size_t)s3 * HH + c0);
        #pragma unroll
        for (int j = 0; j < 8; ++j)
            a[j] += (b2f(v0[j]) + b2f(v1[j])) + (b2f(v2[j]) + b2f(v3[j]));
    }
    for (; e < e1; ++e) {
        ushort8 v = *(const ushort8*)(xb + (size_t)eidx[e] * HH + c0);
        #pragma unroll
        for (int j = 0; j < 8; ++j) a[j] += b2f(v[j]);
    }
    ushort8 o;
    #pragma unroll
    for (int j = 0; j < 8; ++j) o[j] = f2b(a[j]);
    *(ushort8*)(agg + (size_t)node * HH + c0) = o;
}

// Layer-1 scalar aggregate via CSR
__global__ void gather_scalar(const float* __restrict__ x, const int* __restrict__ start,
                              const int* __restrict__ eidx, float* __restrict__ agg0) {
    int i = blockIdx.x * blockDim.x + threadIdx.x;
    if (i >= NN) return;
    float s = 0.f;
    int e1 = start[i + 1];
    for (int e = start[i]; e < e1; ++e) s += x[eidx[e]];
    agg0[i] = s;
}

// x1[i][h] = relu(agg0[i]*w_rel[h] + b[h] + x[i]*w_root[h]); bf16 output only
__global__ void layer1_expand(const float* __restrict__ x,
                              const float* __restrict__ agg0,
                              const float* __restrict__ w_rel,
                              const float* __restrict__ b,
                              const float* __restrict__ w_root,
                              unsigned short* __restrict__ x1b) {
    int idx = blockIdx.x * blockDim.x + threadIdx.x;
    int i = idx >> 7;
    if (i >= NN) return;
    int q = (idx & 127) << 2;
    float a = agg0[i], xv = x[i];
    float4 wr = *(const float4*)&w_rel[q];
    float4 bb = *(const float4*)&b[q];
    float4 wt = *(const float4*)&w_root[q];
    float4 o;
    o.x = fmaxf(fmaf(a, wr.x, fmaf(xv, wt.x, bb.x)), 0.f);
    o.y = fmaxf(fmaf(a, wr.y, fmaf(xv, wt.y, bb.y)), 0.f);
    o.z = fmaxf(fmaf(a, wr.z, fmaf(xv, wt.z, bb.z)), 0.f);
    o.w = fmaxf(fmaf(a, wr.w, fmaf(xv, wt.w, bb.w)), 0.f);
    ushort4 ob = { f2b(o.x), f2b(o.y), f2b(o.z), f2b(o.w) };
    *(ushort4*)&x1b[(size_t)i * HH + q] = ob;
}

// ================= MFMA GEMM — A via LDS, B direct global->VGPR =================
// out = (relu?)(AB@WrT^T + XBp@WoT^T + bias) + resid(bf16)
// 128x128 tile, BK=32, 4 waves (2x2, 64x64 each), R10 dbuf sync structure.
// B (weights, 1 MB total) is L1/L2-hot: each lane loads its B fragment
// directly to registers, double-buffered one K-step ahead. LDS holds only A
// (16 KB) -> halves LDS pipe traffic per K-step (the R11-diagnosed cap).
__device__ inline void gload16(const void* g, void* l) {
    __builtin_amdgcn_global_load_lds(
        (const __attribute__((address_space(1))) unsigned int*)g,
        (__attribute__((address_space(3))) unsigned int*)l,
        16, 0, 0);
}

template<bool RELU, bool F32OUT>
__global__ __launch_bounds__(256, 3) void gemm_mfma(
    const unsigned short* __restrict__ AB, const unsigned short* __restrict__ XBp,
    const unsigned short* __restrict__ WrT, const unsigned short* __restrict__ WoT,
    const float* __restrict__ bias, const unsigned short* __restrict__ residb,
    float* __restrict__ out, unsigned short* __restrict__ outb)
{
    __shared__ unsigned short As[2 * 128 * 32];  // [buf][row][k], k-slots swizzled
    const int tid  = threadIdx.x;
    const int wave = tid >> 6, lane = tid & 63;

    // Bijective XCD-chunked mapping: 3128 blocks = 8 XCDs x 391.
    const int bid = blockIdx.x;
    const int nid = (bid & 7) * 391 + (bid >> 3);
    const int col0 = (nid & 3) << 7;   // n-tile fastest within chunk -> A-panel L2 reuse
    const int row0 = (nid >> 2) << 7;

    const int wr = wave >> 1, wc = wave & 1; // wave's 64x64 quadrant
    const int l16 = lane & 15, lq = lane >> 4;
    const int sRow = lane >> 2;                                  // staging row in chunk
    const int sColSwz = (((lane & 3) ^ ((lane >> 3) & 3)) << 3); // swizzled src k-slot (shorts)
    const int xorslot = ((lq ^ ((lane >> 1) & 3)) << 3);         // read-side slot (shorts)

    // Staged A rows (clamped; stores guarded)
    int rowA[2];
    #pragma unroll
    for (int i = 0; i < 2; ++i) {
        int chunk = (wave << 1) + i;
        int gr = row0 + chunk * 16 + sRow;
        rowA[i] = (gr >= NN) ? (NN - 1) : gr;
    }

    // Per-lane B fragment offsets (elements); + kk per K-step.
    unsigned offB[4];
    #pragma unroll
    for (int n = 0; n < 4; ++n)
        offB[n] = (unsigned)(col0 + wc * 64 + n * 16 + l16) * HH + lq * 8;

    f32x4 acc[4][4];
    #pragma unroll
    for (int m = 0; m < 4; ++m)
        #pragma unroll
        for (int n = 0; n < 4; ++n)
            acc[m][n] = (f32x4){0.f, 0.f, 0.f, 0.f};

    auto STAGE_A = [&](unsigned short* Asb, int t) {
        const int k0 = t << 5;
        const unsigned short* Ap = (k0 < 512) ? AB : XBp;
        const int kk = k0 & 511;
        #pragma unroll
        for (int i = 0; i < 2; ++i) {
            int chunk = (wave << 1) + i;
            gload16(Ap + (size_t)rowA[i] * HH + kk + sColSwz, Asb + chunk * 512);
        }
    };

    auto LOADB = [&](short8 (&bset)[4], int t) {
        const unsigned short* Wp = (t < 16) ? WrT : WoT;
        const unsigned kk = ((unsigned)t & 15u) << 5;
        #pragma unroll
        for (int n = 0; n < 4; ++n)
            bset[n] = *(const short8*)(Wp + offB[n] + kk);
    };

    auto COMPUTE = [&](const unsigned short* Asb, const short8 (&bset)[4]) {
        short8 af[4];
        #pragma unroll
        for (int m = 0; m < 4; ++m)
            af[m] = *(const short8*)(Asb + (wr * 64 + m * 16 + l16) * 32 + xorslot);
        #pragma unroll
        for (int m = 0; m < 4; ++m)
            #pragma unroll
            for (int n = 0; n < 4; ++n)
                acc[m][n] = __builtin_amdgcn_mfma_f32_16x16x32_bf16(af[m], bset[n], acc[m][n], 0, 0, 0);
    };

    unsigned short* A0 = As;
    unsigned short* A1 = As + 4096;
    short8 b0[4], b1[4];

    STAGE_A(A0, 0);
    LOADB(b0, 0);
    __syncthreads();                       // drains vmcnt(0): tile 0 + b0 resident
    #pragma unroll 1
    for (int t = 0; t < 32; t += 2) {
        STAGE_A(A1, t + 1);                // prefetch next A tile
        LOADB(b1, t + 1);                  // prefetch next B frags (regs)
        COMPUTE(A0, b0);
        __syncthreads();
        if (t + 2 < 32) { STAGE_A(A0, t + 2); LOADB(b0, t + 2); }
        COMPUTE(A1, b1);
        __syncthreads();
    }

    // Epilogue: + bias (+relu) + bf16 resid; store f32 or bf16
    float bias_n[4];
    #pragma unroll
    for (int n = 0; n < 4; ++n) bias_n[n] = bias[col0 + wc * 64 + n * 16 + l16];

    #pragma unroll
    for (int m = 0; m < 4; ++m) {
        #pragma unroll
        for (int j = 0; j < 4; ++j) {
            int row = row0 + wr * 64 + m * 16 + lq * 4 + j;
            if (row >= NN) continue;
            #pragma unroll
            for (int n = 0; n < 4; ++n) {
                int col = col0 + wc * 64 + n * 16 + l16;
                size_t off = (size_t)row * HH + col;
                float v = acc[m][n][j] + bias_n[n];
                if (RELU) v = fmaxf(v, 0.f);
                v += b2f(residb[off]);
                if (F32OUT) out[off] = v;
                else        outb[off] = f2b(v);
            }
        }
    }
}

extern "C" void kernel_launch(void* const* d_in, const int* in_sizes, int n_in,
                              void* d_out, int out_size, void* d_ws, size_t ws_size,
                              hipStream_t stream) {
    const float* x   = (const float*)d_in[0];
    const int*   ei  = (const int*)d_in[1];
    const int*   src = ei;
    const int*   dst = ei + EE;
    const float* w_rel1  = (const float*)d_in[2];
    const float* b_rel1  = (const float*)d_in[3];
    const float* w_root1 = (const float*)d_in[4];
    const float* w_rel2  = (const float*)d_in[5];
    const float* b_rel2  = (const float*)d_in[6];
    const float* w_root2 = (const float*)d_in[7];
    const float* w_rel3  = (const float*)d_in[8];
    const float* b_rel3  = (const float*)d_in[9];
    const float* w_root3 = (const float*)d_in[10];
    const float* w_rel4  = (const float*)d_in[11];
    const float* b_rel4  = (const float*)d_in[12];
    const float* w_root4 = (const float*)d_in[13];

    const size_t NH = (size_t)NN * HH;
    unsigned short* XB   = (unsigned short*)d_ws;        // x1 bf16
    unsigned short* XB2  = XB + NH;                      // x2 bf16
    unsigned short* X3B  = XB2 + NH;                     // x3 bf16
    unsigned short* AGB  = X3B + NH;                     // agg bf16
    unsigned short* WT   = AGB + NH;                     // 6 transposed bf16 weights
    float*          agg0 = (float*)(WT + 6 * 262144);
    int*            csr  = (int*)(agg0 + NN);
    int* deg       = csr;
    int* start     = csr + NN;
    int* cursor    = start + NN + 1;
    int* eidx      = cursor + NN;
    int* blockSums = eidx + EE;
    float* out = (float*)d_out;

    unsigned short* WrT2 = WT;
    unsigned short* WoT2 = WT + 1 * 262144;
    unsigned short* WrT3 = WT + 2 * 262144;
    unsigned short* WoT3 = WT + 3 * 262144;
    unsigned short* WrT4 = WT + 4 * 262144;
    unsigned short* WoT4 = WT + 5 * 262144;

    const int gGemm = 3128;  // 782 m-tiles x 4 n-tiles (128x128), XCD-chunked in-kernel

    // ---- CSR build ----
    hipMemsetAsync(deg, 0, NN * sizeof(int), stream);
    histo_deg<<<(EE + 255) / 256, 256, 0, stream>>>(dst, deg);
    scan_reduce<<<NB_SCAN, 256, 0, stream>>>(deg, blockSums);
    scan_top<<<1, 128, 0, stream>>>(blockSums, start);
    scan_down<<<NB_SCAN, 256, 0, stream>>>(deg, blockSums, start, cursor);
    csr_fill<<<(EE + 255) / 256, 256, 0, stream>>>(src, dst, cursor, eidx);

    // ---- Weights -> transposed bf16 ----
    w_transpose<<<1024, 256, 0, stream>>>(w_rel2,  WrT2);
    w_transpose<<<1024, 256, 0, stream>>>(w_root2, WoT2);
    w_transpose<<<1024, 256, 0, stream>>>(w_rel3,  WrT3);
    w_transpose<<<1024, 256, 0, stream>>>(w_root3, WoT3);
    w_transpose<<<1024, 256, 0, stream>>>(w_rel4,  WrT4);
    w_transpose<<<1024, 256, 0, stream>>>(w_root4, WoT4);

    // ---- Layer 1: x1 -> XB (bf16) ----
    gather_scalar<<<(NN + 255) / 256, 256, 0, stream>>>(x, start, eidx, agg0);
    layer1_expand<<<50000, 256, 0, stream>>>(x, agg0, w_rel1, b_rel1, w_root1, XB);

    // ---- Layer 2: x2 = relu(conv(x1)) + x1 -> XB2 (bf16) ----
    gather_rows_b<<<25000, 256, 0, stream>>>(XB, start, eidx, AGB);
    gemm_mfma<true, false><<<gGemm, 256, 0, stream>>>(
        AGB, XB, WrT2, WoT2, b_rel2, XB, nullptr, XB2);

    // ---- Layer 3: x3 = conv(x2) + x2 -> X3B (bf16) ----
    gather_rows_b<<<25000, 256, 0, stream>>>(XB2, start, eidx, AGB);
    gemm_mfma<false, false><<<gGemm, 256, 0, stream>>>(
        AGB, XB2, WrT3, WoT3, b_rel3, XB2, nullptr, X3B);

    // ---- Layer 4: x4 = conv(x3) + x3 -> d_out (f32) ----
    gather_rows_b<<<25000, 256, 0, stream>>>(X3B, start, eidx, AGB);
    gemm_mfma<false, true><<<gGemm, 256, 0, stream>>>(
        AGB, X3B, WrT4, WoT4, b_rel4, X3B, out, nullptr);
}

// Round 13
// 982.610 us; speedup vs baseline: 1.0770x; 1.0770x over previous
//
#include <hip/hip_runtime.h>

#define NN 100000
#define EE 400000
#define HH 512
#define NB_SCAN 98   // ceil(NN/1024)

typedef __attribute__((ext_vector_type(8))) short short8;
typedef __attribute__((ext_vector_type(8))) unsigned short ushort8;
typedef __attribute__((ext_vector_type(4))) float f32x4;

__device__ inline unsigned short f2b(float f) {   // f32 -> bf16 RNE
    unsigned int u = __float_as_uint(f);
    return (unsigned short)((u + 0x7fffu + ((u >> 16) & 1u)) >> 16);
}
__device__ inline float b2f(unsigned short b) {
    return __uint_as_float(((unsigned int)b) << 16);
}

// ================= CSR build =================
__global__ void histo_deg(const int* __restrict__ dst, int* __restrict__ deg) {
    int e = blockIdx.x * blockDim.x + threadIdx.x;
    if (e < EE) atomicAdd(&deg[dst[e]], 1);
}

__global__ void scan_reduce(const int* __restrict__ deg, int* __restrict__ blockSums) {
    __shared__ int s[256];
    int b = blockIdx.x, t = threadIdx.x;
    int base = b * 1024 + t * 4;
    int v = 0;
    #pragma unroll
    for (int j = 0; j < 4; ++j) { int i = base + j; if (i < NN) v += deg[i]; }
    s[t] = v; __syncthreads();
    for (int off = 128; off > 0; off >>= 1) {
        if (t < off) s[t] += s[t + off];
        __syncthreads();
    }
    if (t == 0) blockSums[b] = s[0];
}

__global__ void scan_top(int* __restrict__ blockSums, int* __restrict__ start) {
    __shared__ int s[128];
    int t = threadIdx.x;
    s[t] = (t < NB_SCAN) ? blockSums[t] : 0;
    __syncthreads();
    for (int off = 1; off < 128; off <<= 1) {
        int u = (t >= off) ? s[t - off] : 0;
        __syncthreads();
        s[t] += u;
        __syncthreads();
    }
    if (t < NB_SCAN) blockSums[t] = (t == 0) ? 0 : s[t - 1];  // exclusive
    if (t == 0) start[NN] = EE;
}

__global__ void scan_down(const int* __restrict__ deg, const int* __restrict__ blockSums,
                          int* __restrict__ start, int* __restrict__ cursor) {
    __shared__ int s[256];
    int b = blockIdx.x, t = threadIdx.x;
    int base = b * 1024 + t * 4;
    int v[4]; int sum = 0;
    #pragma unroll
    for (int j = 0; j < 4; ++j) {
        int i = base + j;
        v[j] = (i < NN) ? deg[i] : 0;
        sum += v[j];
    }
    s[t] = sum; __syncthreads();
    for (int off = 1; off < 256; off <<= 1) {
        int u = (t >= off) ? s[t - off] : 0;
        __syncthreads();
        s[t] += u;
        __syncthreads();
    }
    int excl = blockSums[b] + ((t == 0) ? 0 : s[t - 1]);
    #pragma unroll
    for (int j = 0; j < 4; ++j) {
        int i = base + j;
        if (i < NN) { start[i] = excl; cursor[i] = excl; excl += v[j]; }
    }
}

__global__ void csr_fill(const int* __restrict__ src, const int* __restrict__ dst,
                         int* __restrict__ cursor, int* __restrict__ eidx) {
    int e = blockIdx.x * blockDim.x + threadIdx.x;
    if (e < EE) {
        int p = atomicAdd(&cursor[dst[e]], 1);
        eidx[p] = src[e];
    }
}

// ================= Weight prep =================
// wt[n][k] = bf16(w[k][n] + (ADDI && k==n))
__global__ void w_transpose(const float* __restrict__ w, unsigned short* __restrict__ wt, int addI) {
    int idx = blockIdx.x * 256 + threadIdx.x;  // n*512 + k
    int n = idx >> 9, k = idx & 511;
    float v = w[(size_t)k * HH + n] + ((addI && k == n) ? 1.f : 0.f);
    wt[idx] = f2b(v);
}
// wb[k][j] = bf16(w[k][j] + (ADDI && k==j))
__global__ void w_convert(const float* __restrict__ w, unsigned short* __restrict__ wb, int addI) {
    int idx = blockIdx.x * 256 + threadIdx.x;  // k*512 + j
    int k = idx >> 9, j = idx & 511;
    float v = w[idx] + ((addI && k == j) ? 1.f : 0.f);
    wb[idx] = f2b(v);
}
// c1[n] = sum_j b3[j]*Wr4[j][n];  c2[n] = sum_j b3[j]*Wo4[j][n] + b3[n] + b4[n]
__global__ void cvec(const float* __restrict__ b3, const float* __restrict__ Wr4,
                     const float* __restrict__ Wo4, const float* __restrict__ b4,
                     float* __restrict__ c1, float* __restrict__ c2) {
    int n = blockIdx.x * 256 + threadIdx.x;
    if (n >= HH) return;
    float a1 = 0.f, a2 = 0.f;
    for (int j = 0; j < HH; ++j) {
        float bj = b3[j];
        a1 = fmaf(bj, Wr4[(size_t)j * HH + n], a1);
        a2 = fmaf(bj, Wo4[(size_t)j * HH + n], a2);
    }
    c1[n] = a1;
    c2[n] = a2 + b3[n] + b4[n];
}

// ================= Aggregation: bf16 gather, one wave per node =================
__global__ __launch_bounds__(256) void gather_rows_b(
    const unsigned short* __restrict__ xb, const int* __restrict__ start,
    const int* __restrict__ eidx, unsigned short* __restrict__ agg)
{
    int node = blockIdx.x * 4 + (threadIdx.x >> 6);
    if (node >= NN) return;
    int c0 = (threadIdx.x & 63) << 3;   // 8 bf16 per lane
    float a[8] = {0.f,0.f,0.f,0.f,0.f,0.f,0.f,0.f};
    int e0 = start[node], e1 = start[node + 1];
    int e = e0;
    for (; e + 4 <= e1; e += 4) {
        int s0 = eidx[e], s1 = eidx[e + 1], s2 = eidx[e + 2], s3 = eidx[e + 3];
        ushort8 v0 = *(const ushort8*)(xb + (size_t)s0 * HH + c0);
        ushort8 v1 = *(const ushort8*)(xb + (size_t)s1 * HH + c0);
        ushort8 v2 = *(const ushort8*)(xb + (size_t)s2 * HH + c0);
        ushort8 v3 = *(const ushort8*)(xb + (size_t)s3 * HH + c0);
        #pragma unroll
        for (int j = 0; j < 8; ++j)
            a[j] += (b2f(v0[j]) + b2f(v1[j])) + (b2f(v2[j]) + b2f(v3[j]));
    }
    for (; e < e1; ++e) {
        ushort8 v = *(const ushort8*)(xb + (size_t)eidx[e] * HH + c0);
        #pragma unroll
        for (int j = 0; j < 8; ++j) a[j] += b2f(v[j]);
    }
    ushort8 o;
    #pragma unroll
    for (int j = 0; j < 8; ++j) o[j] = f2b(a[j]);
    *(ushort8*)(agg + (size_t)node * HH + c0) = o;
}

// Layer-1 scalar aggregate via CSR
__global__ void gather_scalar(const float* __restrict__ x, const int* __restrict__ start,
                              const int* __restrict__ eidx, float* __restrict__ agg0) {
    int i = blockIdx.x * blockDim.x + threadIdx.x;
    if (i >= NN) return;
    float s = 0.f;
    int e1 = start[i + 1];
    for (int e = start[i]; e < e1; ++e) s += x[eidx[e]];
    agg0[i] = s;
}

// x1[i][h] = relu(agg0[i]*w_rel[h] + b[h] + x[i]*w_root[h]); bf16
__global__ void layer1_expand(const float* __restrict__ x,
                              const float* __restrict__ agg0,
                              const float* __restrict__ w_rel,
                              const float* __restrict__ b,
                              const float* __restrict__ w_root,
                              unsigned short* __restrict__ x1b) {
    int idx = blockIdx.x * blockDim.x + threadIdx.x;
    int i = idx >> 7;
    if (i >= NN) return;
    int q = (idx & 127) << 2;
    float a = agg0[i], xv = x[i];
    float4 wr = *(const float4*)&w_rel[q];
    float4 bb = *(const float4*)&b[q];
    float4 wt = *(const float4*)&w_root[q];
    float4 o;
    o.x = fmaxf(fmaf(a, wr.x, fmaf(xv, wt.x, bb.x)), 0.f);
    o.y = fmaxf(fmaf(a, wr.y, fmaf(xv, wt.y, bb.y)), 0.f);
    o.z = fmaxf(fmaf(a, wr.z, fmaf(xv, wt.z, bb.z)), 0.f);
    o.w = fmaxf(fmaf(a, wr.w, fmaf(xv, wt.w, bb.w)), 0.f);
    ushort4 ob = { f2b(o.x), f2b(o.y), f2b(o.z), f2b(o.w) };
    *(ushort4*)&x1b[(size_t)i * HH + q] = ob;
}

// ================= shared GEMM machinery (R10 structure) =================
__device__ inline void gload16(const void* g, void* l) {
    __builtin_amdgcn_global_load_lds(
        (const __attribute__((address_space(1))) unsigned int*)g,
        (__attribute__((address_space(3))) unsigned int*)l,
        16, 0, 0);
}

// Layer-2 GEMM: out = relu(AB@WrT^T + XBp@WoT^T + bias) + resid(bf16) -> bf16
__global__ __launch_bounds__(256, 3) void gemm_l2(
    const unsigned short* __restrict__ AB, const unsigned short* __restrict__ XBp,
    const unsigned short* __restrict__ WrT, const unsigned short* __restrict__ WoT,
    const float* __restrict__ bias, const unsigned short* __restrict__ residb,
    unsigned short* __restrict__ outb)
{
    __shared__ unsigned short As[2 * 128 * 32];
    __shared__ unsigned short Bs[2 * 128 * 32];
    const int tid  = threadIdx.x;
    const int wave = tid >> 6, lane = tid & 63;
    const int bid = blockIdx.x;
    const int nid = (bid & 7) * 391 + (bid >> 3);
    const int col0 = (nid & 3) << 7;
    const int row0 = (nid >> 2) << 7;
    const int wr = wave >> 1, wc = wave & 1;
    const int l16 = lane & 15, lq = lane >> 4;
    const int sRow = lane >> 2;
    const int sColSwz = (((lane & 3) ^ ((lane >> 3) & 3)) << 3);
    const int xorslot = ((lq ^ ((lane >> 1) & 3)) << 3);

    int rowA[2], colB[2];
    #pragma unroll
    for (int i = 0; i < 2; ++i) {
        int chunk = (wave << 1) + i;
        int gr = row0 + chunk * 16 + sRow;
        rowA[i] = (gr >= NN) ? (NN - 1) : gr;
        colB[i] = col0 + chunk * 16 + sRow;
    }

    f32x4 acc[4][4];
    #pragma unroll
    for (int m = 0; m < 4; ++m)
        #pragma unroll
        for (int n = 0; n < 4; ++n) acc[m][n] = (f32x4){0.f,0.f,0.f,0.f};

    auto STAGE = [&](unsigned short* Asb, unsigned short* Bsb, int t) {
        const int k0 = t << 5;
        const unsigned short* Ap = (k0 < 512) ? AB  : XBp;
        const unsigned short* Wp = (k0 < 512) ? WrT : WoT;
        const int kk = k0 & 511;
        #pragma unroll
        for (int i = 0; i < 2; ++i) {
            int chunk = (wave << 1) + i;
            gload16(Ap + (size_t)rowA[i] * HH + kk + sColSwz, Asb + chunk * 512);
            gload16(Wp + (size_t)colB[i] * HH + kk + sColSwz, Bsb + chunk * 512);
        }
    };
    auto COMPUTE = [&](const unsigned short* Asb, const unsigned short* Bsb) {
        short8 af[4], bfv[4];
        #pragma unroll
        for (int m = 0; m < 4; ++m)
            af[m] = *(const short8*)(Asb + (wr * 64 + m * 16 + l16) * 32 + xorslot);
        #pragma unroll
        for (int n = 0; n < 4; ++n)
            bfv[n] = *(const short8*)(Bsb + (wc * 64 + n * 16 + l16) * 32 + xorslot);
        #pragma unroll
        for (int m = 0; m < 4; ++m)
            #pragma unroll
            for (int n = 0; n < 4; ++n)
                acc[m][n] = __builtin_amdgcn_mfma_f32_16x16x32_bf16(af[m], bfv[n], acc[m][n], 0, 0, 0);
    };

    unsigned short *A0 = As, *A1 = As + 4096, *B0 = Bs, *B1 = Bs + 4096;
    STAGE(A0, B0, 0);
    __syncthreads();
    #pragma unroll 1
    for (int t = 0; t < 32; t += 2) {
        STAGE(A1, B1, t + 1);
        COMPUTE(A0, B0);
        __syncthreads();
        if (t + 2 < 32) STAGE(A0, B0, t + 2);
        COMPUTE(A1, B1);
        __syncthreads();
    }

    float bias_n[4];
    #pragma unroll
    for (int n = 0; n < 4; ++n) bias_n[n] = bias[col0 + wc * 64 + n * 16 + l16];
    #pragma unroll
    for (int m = 0; m < 4; ++m) {
        #pragma unroll
        for (int j = 0; j < 4; ++j) {
            int row = row0 + wr * 64 + m * 16 + lq * 4 + j;
            if (row >= NN) continue;
            #pragma unroll
            for (int n = 0; n < 4; ++n) {
                int col = col0 + wc * 64 + n * 16 + l16;
                size_t off = (size_t)row * HH + col;
                float v = fmaxf(acc[m][n][j] + bias_n[n], 0.f) + b2f(residb[off]);
                outb[off] = f2b(v);
            }
        }
    }
}

// Fused layers 3+4: out = G2@P1^T + G1@P2^T + X2@P3^T + deg*c1 + c2  (K=1536)
__global__ __launch_bounds__(256, 3) void gemm_f34(
    const unsigned short* __restrict__ G2, const unsigned short* __restrict__ G1,
    const unsigned short* __restrict__ X2,
    const unsigned short* __restrict__ P1T, const unsigned short* __restrict__ P2T,
    const unsigned short* __restrict__ P3T,
    const float* __restrict__ c1, const float* __restrict__ c2,
    const int* __restrict__ deg, float* __restrict__ out)
{
    __shared__ unsigned short As[2 * 128 * 32];
    __shared__ unsigned short Bs[2 * 128 * 32];
    const int tid  = threadIdx.x;
    const int wave = tid >> 6, lane = tid & 63;
    const int bid = blockIdx.x;
    const int nid = (bid & 7) * 391 + (bid >> 3);
    const int col0 = (nid & 3) << 7;
    const int row0 = (nid >> 2) << 7;
    const int wr = wave >> 1, wc = wave & 1;
    const int l16 = lane & 15, lq = lane >> 4;
    const int sRow = lane >> 2;
    const int sColSwz = (((lane & 3) ^ ((lane >> 3) & 3)) << 3);
    const int xorslot = ((lq ^ ((lane >> 1) & 3)) << 3);

    int rowA[2], colB[2];
    #pragma unroll
    for (int i = 0; i < 2; ++i) {
        int chunk = (wave << 1) + i;
        int gr = row0 + chunk * 16 + sRow;
        rowA[i] = (gr >= NN) ? (NN - 1) : gr;
        colB[i] = col0 + chunk * 16 + sRow;
    }

    f32x4 acc[4][4];
    #pragma unroll
    for (int m = 0; m < 4; ++m)
        #pragma unroll
        for (int n = 0; n < 4; ++n) acc[m][n] = (f32x4){0.f,0.f,0.f,0.f};

    auto STAGE = [&](unsigned short* Asb, unsigned short* Bsb, int t) {
        const int s = t >> 4;
        const unsigned short* Ap = (s == 0) ? G2  : ((s == 1) ? G1  : X2);
        const unsigned short* Wp = (s == 0) ? P1T : ((s == 1) ? P2T : P3T);
        const int kk = (t & 15) << 5;
        #pragma unroll
        for (int i = 0; i < 2; ++i) {
            int chunk = (wave << 1) + i;
            gload16(Ap + (size_t)rowA[i] * HH + kk + sColSwz, Asb + chunk * 512);
            gload16(Wp + (size_t)colB[i] * HH + kk + sColSwz, Bsb + chunk * 512);
        }
    };
    auto COMPUTE = [&](const unsigned short* Asb, const unsigned short* Bsb) {
        short8 af[4], bfv[4];
        #pragma unroll
        for (int m = 0; m < 4; ++m)
            af[m] = *(const short8*)(Asb + (wr * 64 + m * 16 + l16) * 32 + xorslot);
        #pragma unroll
        for (int n = 0; n < 4; ++n)
            bfv[n] = *(const short8*)(Bsb + (wc * 64 + n * 16 + l16) * 32 + xorslot);
        #pragma unroll
        for (int m = 0; m < 4; ++m)
            #pragma unroll
            for (int n = 0; n < 4; ++n)
                acc[m][n] = __builtin_amdgcn_mfma_f32_16x16x32_bf16(af[m], bfv[n], acc[m][n], 0, 0, 0);
    };

    unsigned short *A0 = As, *A1 = As + 4096, *B0 = Bs, *B1 = Bs + 4096;
    STAGE(A0, B0, 0);
    __syncthreads();
    #pragma unroll 1
    for (int t = 0; t < 48; t += 2) {
        STAGE(A1, B1, t + 1);
        COMPUTE(A0, B0);
        __syncthreads();
        if (t + 2 < 48) STAGE(A0, B0, t + 2);
        COMPUTE(A1, B1);
        __syncthreads();
    }

    float c1_n[4], c2_n[4];
    #pragma unroll
    for (int n = 0; n < 4; ++n) {
        int col = col0 + wc * 64 + n * 16 + l16;
        c1_n[n] = c1[col];
        c2_n[n] = c2[col];
    }
    #pragma unroll
    for (int m = 0; m < 4; ++m) {
        #pragma unroll
        for (int j = 0; j < 4; ++j) {
            int row = row0 + wr * 64 + m * 16 + lq * 4 + j;
            if (row >= NN) continue;
            float dg = (float)deg[row];
            #pragma unroll
            for (int n = 0; n < 4; ++n) {
                int col = col0 + wc * 64 + n * 16 + l16;
                out[(size_t)row * HH + col] = acc[m][n][j] + dg * c1_n[n] + c2_n[n];
            }
        }
    }
}

// Composite 512x512 weight products: out[i][h] = sum_k A(i,k)*W(h,k)  (bf16 out)
// NSRC=1: K=512 (A0,W0). NSRC=2: K=1024 (A0,W0)+(A1,W1). Grid = 16 blocks.
template<int NSRC>
__global__ __launch_bounds__(256) void gemm_cmp(
    const unsigned short* __restrict__ A0p, const unsigned short* __restrict__ W0p,
    const unsigned short* __restrict__ A1p, const unsigned short* __restrict__ W1p,
    unsigned short* __restrict__ outb)
{
    __shared__ unsigned short As[2 * 128 * 32];
    __shared__ unsigned short Bs[2 * 128 * 32];
    const int tid  = threadIdx.x;
    const int wave = tid >> 6, lane = tid & 63;
    const int col0 = (blockIdx.x & 3) << 7;
    const int row0 = (blockIdx.x >> 2) << 7;
    const int wr = wave >> 1, wc = wave & 1;
    const int l16 = lane & 15, lq = lane >> 4;
    const int sRow = lane >> 2;
    const int sColSwz = (((lane & 3) ^ ((lane >> 3) & 3)) << 3);
    const int xorslot = ((lq ^ ((lane >> 1) & 3)) << 3);

    int rowA[2], colB[2];
    #pragma unroll
    for (int i = 0; i < 2; ++i) {
        int chunk = (wave << 1) + i;
        rowA[i] = row0 + chunk * 16 + sRow;
        colB[i] = col0 + chunk * 16 + sRow;
    }

    f32x4 acc[4][4];
    #pragma unroll
    for (int m = 0; m < 4; ++m)
        #pragma unroll
        for (int n = 0; n < 4; ++n) acc[m][n] = (f32x4){0.f,0.f,0.f,0.f};

    auto STAGE = [&](unsigned short* Asb, unsigned short* Bsb, int t) {
        const unsigned short* Ap = (NSRC == 1 || t < 16) ? A0p : A1p;
        const unsigned short* Wp = (NSRC == 1 || t < 16) ? W0p : W1p;
        const int kk = (t & 15) << 5;
        #pragma unroll
        for (int i = 0; i < 2; ++i) {
            int chunk = (wave << 1) + i;
            gload16(Ap + (size_t)rowA[i] * HH + kk + sColSwz, Asb + chunk * 512);
            gload16(Wp + (size_t)colB[i] * HH + kk + sColSwz, Bsb + chunk * 512);
        }
    };
    auto COMPUTE = [&](const unsigned short* Asb, const unsigned short* Bsb) {
        short8 af[4], bfv[4];
        #pragma unroll
        for (int m = 0; m < 4; ++m)
            af[m] = *(const short8*)(Asb + (wr * 64 + m * 16 + l16) * 32 + xorslot);
        #pragma unroll
        for (int n = 0; n < 4; ++n)
            bfv[n] = *(const short8*)(Bsb + (wc * 64 + n * 16 + l16) * 32 + xorslot);
        #pragma unroll
        for (int m = 0; m < 4; ++m)
            #pragma unroll
            for (int n = 0; n < 4; ++n)
                acc[m][n] = __builtin_amdgcn_mfma_f32_16x16x32_bf16(af[m], bfv[n], acc[m][n], 0, 0, 0);
    };

    const int NT = NSRC * 16;
    unsigned short *A0 = As, *A1 = As + 4096, *B0 = Bs, *B1 = Bs + 4096;
    STAGE(A0, B0, 0);
    __syncthreads();
    #pragma unroll 1
    for (int t = 0; t < NT; t += 2) {
        STAGE(A1, B1, t + 1);
        COMPUTE(A0, B0);
        __syncthreads();
        if (t + 2 < NT) STAGE(A0, B0, t + 2);
        COMPUTE(A1, B1);
        __syncthreads();
    }

    #pragma unroll
    for (int m = 0; m < 4; ++m)
        #pragma unroll
        for (int j = 0; j < 4; ++j) {
            int row = row0 + wr * 64 + m * 16 + lq * 4 + j;
            #pragma unroll
            for (int n = 0; n < 4; ++n) {
                int col = col0 + wc * 64 + n * 16 + l16;
                outb[(size_t)row * HH + col] = f2b(acc[m][n][j]);
            }
        }
}

extern "C" void kernel_launch(void* const* d_in, const int* in_sizes, int n_in,
                              void* d_out, int out_size, void* d_ws, size_t ws_size,
                              hipStream_t stream) {
    const float* x   = (const float*)d_in[0];
    const int*   ei  = (const int*)d_in[1];
    const int*   src = ei;
    const int*   dst = ei + EE;
    const float* w_rel1  = (const float*)d_in[2];
    const float* b_rel1  = (const float*)d_in[3];
    const float* w_root1 = (const float*)d_in[4];
    const float* w_rel2  = (const float*)d_in[5];
    const float* b_rel2  = (const float*)d_in[6];
    const float* w_root2 = (const float*)d_in[7];
    const float* w_rel3  = (const float*)d_in[8];
    const float* b_rel3  = (const float*)d_in[9];
    const float* w_root3 = (const float*)d_in[10];
    const float* w_rel4  = (const float*)d_in[11];
    const float* b_rel4  = (const float*)d_in[12];
    const float* w_root4 = (const float*)d_in[13];

    const size_t NH = (size_t)NN * HH;
    const size_t WSZ = 262144;
    unsigned short* XB   = (unsigned short*)d_ws;        // x1 bf16
    unsigned short* XB2  = XB + NH;                      // x2 bf16
    unsigned short* AGB  = XB2 + NH;                     // agg / G1
    unsigned short* AGB2 = AGB + NH;                     // G2
    unsigned short* WT   = AGB2 + NH;
    unsigned short* WrT2 = WT;                 // T(w_rel2)
    unsigned short* WoT2 = WT + 1 * WSZ;       // T(w_root2)
    unsigned short* WrT4 = WT + 2 * WSZ;       // T(w_rel4)
    unsigned short* M4T  = WT + 3 * WSZ;       // T(w_root4 + I)
    unsigned short* Wr3b = WT + 4 * WSZ;       // bf16(w_rel3)
    unsigned short* M3b  = WT + 5 * WSZ;       // bf16(w_root3 + I)
    unsigned short* P1T  = WT + 6 * WSZ;       // T(Wr3·Wr4)
    unsigned short* P2T  = WT + 7 * WSZ;       // T(M3·Wr4 + Wr3·M4)
    unsigned short* P3T  = WT + 8 * WSZ;       // T(M3·M4)
    float* c1   = (float*)(WT + 9 * WSZ);
    float* c2   = c1 + HH;
    float* agg0 = c2 + HH;
    int*   csr  = (int*)(agg0 + NN);
    int* deg       = csr;
    int* start     = csr + NN;
    int* cursor    = start + NN + 1;
    int* eidx      = cursor + NN;
    int* blockSums = eidx + EE;
    float* out = (float*)d_out;

    const int gGemm = 3128;  // 782 m-tiles x 4 n-tiles, XCD-chunked in-kernel

    // ---- CSR build ----
    hipMemsetAsync(deg, 0, NN * sizeof(int), stream);
    histo_deg<<<(EE + 255) / 256, 256, 0, stream>>>(dst, deg);
    scan_reduce<<<NB_SCAN, 256, 0, stream>>>(deg, blockSums);
    scan_top<<<1, 128, 0, stream>>>(blockSums, start);
    scan_down<<<NB_SCAN, 256, 0, stream>>>(deg, blockSums, start, cursor);
    csr_fill<<<(EE + 255) / 256, 256, 0, stream>>>(src, dst, cursor, eidx);

    // ---- Weight prep ----
    w_transpose<<<1024, 256, 0, stream>>>(w_rel2,  WrT2, 0);
    w_transpose<<<1024, 256, 0, stream>>>(w_root2, WoT2, 0);
    w_transpose<<<1024, 256, 0, stream>>>(w_rel4,  WrT4, 0);
    w_transpose<<<1024, 256, 0, stream>>>(w_root4, M4T,  1);
    w_convert <<<1024, 256, 0, stream>>>(w_rel3,  Wr3b, 0);
    w_convert <<<1024, 256, 0, stream>>>(w_root3, M3b,  1);
    // Composites: P1T = WrT4·Wr3b^T, P2T = WrT4·M3b^T + M4T·Wr3b^T, P3T = M4T·M3b^T
    gemm_cmp<1><<<16, 256, 0, stream>>>(WrT4, Wr3b, nullptr, nullptr, P1T);
    gemm_cmp<2><<<16, 256, 0, stream>>>(WrT4, M3b,  M4T, Wr3b,       P2T);
    gemm_cmp<1><<<16, 256, 0, stream>>>(M4T,  M3b,  nullptr, nullptr, P3T);
    cvec<<<2, 256, 0, stream>>>(b_rel3, w_rel4, w_root4, b_rel4, c1, c2);

    // ---- Layer 1: x1 -> XB (bf16) ----
    gather_scalar<<<(NN + 255) / 256, 256, 0, stream>>>(x, start, eidx, agg0);
    layer1_expand<<<50000, 256, 0, stream>>>(x, agg0, w_rel1, b_rel1, w_root1, XB);

    // ---- Layer 2: x2 = relu(conv(x1)) + x1 -> XB2 (bf16) ----
    gather_rows_b<<<25000, 256, 0, stream>>>(XB, start, eidx, AGB);
    gemm_l2<<<gGemm, 256, 0, stream>>>(AGB, XB, WrT2, WoT2, b_rel2, XB, XB2);

    // ---- Fused layers 3+4 ----
    gather_rows_b<<<25000, 256, 0, stream>>>(XB2, start, eidx, AGB);   // G1 = A(x2)
    gather_rows_b<<<25000, 256, 0, stream>>>(AGB, start, eidx, AGB2);  // G2 = A(G1)
    gemm_f34<<<gGemm, 256, 0, stream>>>(AGB2, AGB, XB2, P1T, P2T, P3T, c1, c2, deg, out);
}

// Round 14
// 819.399 us; speedup vs baseline: 1.2916x; 1.1992x over previous
//
#include <hip/hip_runtime.h>

#define NN 100000
#define EE 400000
#define HH 512
#define NB_SCAN 98   // ceil(NN/1024)

typedef __attribute__((ext_vector_type(8))) short short8;
typedef __attribute__((ext_vector_type(8))) unsigned short ushort8;
typedef __attribute__((ext_vector_type(4))) float f32x4;

__device__ inline unsigned short f2b(float f) {   // f32 -> bf16 RNE
    unsigned int u = __float_as_uint(f);
    return (unsigned short)((u + 0x7fffu + ((u >> 16) & 1u)) >> 16);
}
__device__ inline float b2f(unsigned short b) {
    return __uint_as_float(((unsigned int)b) << 16);
}

// ================= CSR build =================
__global__ void histo_deg(const int* __restrict__ dst, int* __restrict__ deg) {
    int e = blockIdx.x * blockDim.x + threadIdx.x;
    if (e < EE) atomicAdd(&deg[dst[e]], 1);
}

__global__ void scan_reduce(const int* __restrict__ deg, int* __restrict__ blockSums) {
    __shared__ int s[256];
    int b = blockIdx.x, t = threadIdx.x;
    int base = b * 1024 + t * 4;
    int v = 0;
    #pragma unroll
    for (int j = 0; j < 4; ++j) { int i = base + j; if (i < NN) v += deg[i]; }
    s[t] = v; __syncthreads();
    for (int off = 128; off > 0; off >>= 1) {
        if (t < off) s[t] += s[t + off];
        __syncthreads();
    }
    if (t == 0) blockSums[b] = s[0];
}

__global__ void scan_top(int* __restrict__ blockSums, int* __restrict__ start) {
    __shared__ int s[128];
    int t = threadIdx.x;
    s[t] = (t < NB_SCAN) ? blockSums[t] : 0;
    __syncthreads();
    for (int off = 1; off < 128; off <<= 1) {
        int u = (t >= off) ? s[t - off] : 0;
        __syncthreads();
        s[t] += u;
        __syncthreads();
    }
    if (t < NB_SCAN) blockSums[t] = (t == 0) ? 0 : s[t - 1];  // exclusive
    if (t == 0) start[NN] = EE;
}

__global__ void scan_down(const int* __restrict__ deg, const int* __restrict__ blockSums,
                          int* __restrict__ start, int* __restrict__ cursor) {
    __shared__ int s[256];
    int b = blockIdx.x, t = threadIdx.x;
    int base = b * 1024 + t * 4;
    int v[4]; int sum = 0;
    #pragma unroll
    for (int j = 0; j < 4; ++j) {
        int i = base + j;
        v[j] = (i < NN) ? deg[i] : 0;
        sum += v[j];
    }
    s[t] = sum; __syncthreads();
    for (int off = 1; off < 256; off <<= 1) {
        int u = (t >= off) ? s[t - off] : 0;
        __syncthreads();
        s[t] += u;
        __syncthreads();
    }
    int excl = blockSums[b] + ((t == 0) ? 0 : s[t - 1]);
    #pragma unroll
    for (int j = 0; j < 4; ++j) {
        int i = base + j;
        if (i < NN) { start[i] = excl; cursor[i] = excl; excl += v[j]; }
    }
}

__global__ void csr_fill(const int* __restrict__ src, const int* __restrict__ dst,
                         int* __restrict__ cursor, int* __restrict__ eidx) {
    int e = blockIdx.x * blockDim.x + threadIdx.x;
    if (e < EE) {
        int p = atomicAdd(&cursor[dst[e]], 1);
        eidx[p] = src[e];
    }
}

// ================= Weight transpose + bf16 convert =================
__global__ void w_transpose(const float* __restrict__ w, unsigned short* __restrict__ wt) {
    int idx = blockIdx.x * 256 + threadIdx.x;  // n*512 + k, k fastest
    int n = idx >> 9, k = idx & 511;
    wt[idx] = f2b(w[(size_t)k * HH + n]);
}

// ================= Aggregation: bf16 gather, one wave per node =================
// 4-deep software pipeline: issue 4 independent row loads per iteration (MLP).
__global__ __launch_bounds__(256) void gather_rows_b(
    const unsigned short* __restrict__ xb, const int* __restrict__ start,
    const int* __restrict__ eidx, unsigned short* __restrict__ agg)
{
    int node = blockIdx.x * 4 + (threadIdx.x >> 6);
    if (node >= NN) return;
    int c0 = (threadIdx.x & 63) << 3;   // 8 bf16 per lane
    float a[8] = {0.f,0.f,0.f,0.f,0.f,0.f,0.f,0.f};
    int e0 = start[node], e1 = start[node + 1];
    int e = e0;
    for (; e + 4 <= e1; e += 4) {
        int s0 = eidx[e], s1 = eidx[e + 1], s2 = eidx[e + 2], s3 = eidx[e + 3];
        ushort8 v0 = *(const ushort8*)(xb + (size_t)s0 * HH + c0);
        ushort8 v1 = *(const ushort8*)(xb + (size_t)s1 * HH + c0);
        ushort8 v2 = *(const ushort8*)(xb + (size_t)s2 * HH + c0);
        ushort8 v3 = *(const ushort8*)(xb + (size_t)s3 * HH + c0);
        #pragma unroll
        for (int j = 0; j < 8; ++j)
            a[j] += (b2f(v0[j]) + b2f(v1[j])) + (b2f(v2[j]) + b2f(v3[j]));
    }
    for (; e < e1; ++e) {
        ushort8 v = *(const ushort8*)(xb + (size_t)eidx[e] * HH + c0);
        #pragma unroll
        for (int j = 0; j < 8; ++j) a[j] += b2f(v[j]);
    }
    ushort8 o;
    #pragma unroll
    for (int j = 0; j < 8; ++j) o[j] = f2b(a[j]);
    *(ushort8*)(agg + (size_t)node * HH + c0) = o;
}

// Layer-1 scalar aggregate via CSR
__global__ void gather_scalar(const float* __restrict__ x, const int* __restrict__ start,
                              const int* __restrict__ eidx, float* __restrict__ agg0) {
    int i = blockIdx.x * blockDim.x + threadIdx.x;
    if (i >= NN) return;
    float s = 0.f;
    int e1 = start[i + 1];
    for (int e = start[i]; e < e1; ++e) s += x[eidx[e]];
    agg0[i] = s;
}

// x1[i][h] = relu(agg0[i]*w_rel[h] + b[h] + x[i]*w_root[h]); bf16 output only
__global__ void layer1_expand(const float* __restrict__ x,
                              const float* __restrict__ agg0,
                              const float* __restrict__ w_rel,
                              const float* __restrict__ b,
                              const float* __restrict__ w_root,
                              unsigned short* __restrict__ x1b) {
    int idx = blockIdx.x * blockDim.x + threadIdx.x;
    int i = idx >> 7;
    if (i >= NN) return;
    int q = (idx & 127) << 2;
    float a = agg0[i], xv = x[i];
    float4 wr = *(const float4*)&w_rel[q];
    float4 bb = *(const float4*)&b[q];
    float4 wt = *(const float4*)&w_root[q];
    float4 o;
    o.x = fmaxf(fmaf(a, wr.x, fmaf(xv, wt.x, bb.x)), 0.f);
    o.y = fmaxf(fmaf(a, wr.y, fmaf(xv, wt.y, bb.y)), 0.f);
    o.z = fmaxf(fmaf(a, wr.z, fmaf(xv, wt.z, bb.z)), 0.f);
    o.w = fmaxf(fmaf(a, wr.w, fmaf(xv, wt.w, bb.w)), 0.f);
    ushort4 ob = { f2b(o.x), f2b(o.y), f2b(o.z), f2b(o.w) };
    *(ushort4*)&x1b[(size_t)i * HH + q] = ob;
}

// ================= MFMA GEMM (R10 structure + coalesced bf16 epilogue) =================
// out = (relu?)(AB@WrT^T + XBp@WoT^T + bias) + resid(bf16)
// 128x128 tile, BK=32, 4 waves, double-buffered LDS, one barrier per K-step.
// LDS k-slots XOR-swizzled both sides (conflict-free R4-R13).
// bf16-out path: stage C-tile in LDS (16B-group XOR swizzle), then coalesced
// ushort8 resid-read + store (fixes 2x sectored-write amplification).
__device__ inline void gload16(const void* g, void* l) {
    __builtin_amdgcn_global_load_lds(
        (const __attribute__((address_space(1))) unsigned int*)g,
        (__attribute__((address_space(3))) unsigned int*)l,
        16, 0, 0);
}

template<bool RELU, bool F32OUT>
__global__ __launch_bounds__(256, 3) void gemm_mfma(
    const unsigned short* __restrict__ AB, const unsigned short* __restrict__ XBp,
    const unsigned short* __restrict__ WrT, const unsigned short* __restrict__ WoT,
    const float* __restrict__ bias, const unsigned short* __restrict__ residb,
    float* __restrict__ out, unsigned short* __restrict__ outb)
{
    __shared__ unsigned short LDS[16384];        // As | Bs, reused as C-tile in epilogue
    unsigned short* As = LDS;                    // 2 x 128 x 32
    unsigned short* Bs = LDS + 8192;             // 2 x 128 x 32
    const int tid  = threadIdx.x;
    const int wave = tid >> 6, lane = tid & 63;

    // Bijective XCD-chunked mapping: 3128 blocks = 8 XCDs x 391.
    const int bid = blockIdx.x;
    const int nid = (bid & 7) * 391 + (bid >> 3);
    const int col0 = (nid & 3) << 7;   // n-tile fastest -> A-panel L2 reuse
    const int row0 = (nid >> 2) << 7;

    const int wr = wave >> 1, wc = wave & 1; // wave's 64x64 quadrant
    const int l16 = lane & 15, lq = lane >> 4;
    const int sRow = lane >> 2;                                  // staging row in chunk
    const int sColSwz = (((lane & 3) ^ ((lane >> 3) & 3)) << 3); // swizzled src k-slot (shorts)
    const int xorslot = ((lq ^ ((lane >> 1) & 3)) << 3);         // read-side slot (shorts)

    int rowA[2], colB[2];
    #pragma unroll
    for (int i = 0; i < 2; ++i) {
        int chunk = (wave << 1) + i;
        int gr = row0 + chunk * 16 + sRow;
        rowA[i] = (gr >= NN) ? (NN - 1) : gr;
        colB[i] = col0 + chunk * 16 + sRow;
    }

    f32x4 acc[4][4];
    #pragma unroll
    for (int m = 0; m < 4; ++m)
        #pragma unroll
        for (int n = 0; n < 4; ++n) acc[m][n] = (f32x4){0.f,0.f,0.f,0.f};

    auto STAGE = [&](unsigned short* Asb, unsigned short* Bsb, int t) {
        const int k0 = t << 5;
        const unsigned short* Ap = (k0 < 512) ? AB  : XBp;
        const unsigned short* Wp = (k0 < 512) ? WrT : WoT;
        const int kk = k0 & 511;
        #pragma unroll
        for (int i = 0; i < 2; ++i) {
            int chunk = (wave << 1) + i;
            gload16(Ap + (size_t)rowA[i] * HH + kk + sColSwz, Asb + chunk * 512);
            gload16(Wp + (size_t)colB[i] * HH + kk + sColSwz, Bsb + chunk * 512);
        }
    };
    auto COMPUTE = [&](const unsigned short* Asb, const unsigned short* Bsb) {
        short8 af[4], bfv[4];
        #pragma unroll
        for (int m = 0; m < 4; ++m)
            af[m] = *(const short8*)(Asb + (wr * 64 + m * 16 + l16) * 32 + xorslot);
        #pragma unroll
        for (int n = 0; n < 4; ++n)
            bfv[n] = *(const short8*)(Bsb + (wc * 64 + n * 16 + l16) * 32 + xorslot);
        #pragma unroll
        for (int m = 0; m < 4; ++m)
            #pragma unroll
            for (int n = 0; n < 4; ++n)
                acc[m][n] = __builtin_amdgcn_mfma_f32_16x16x32_bf16(af[m], bfv[n], acc[m][n], 0, 0, 0);
    };

    unsigned short *A0 = As, *A1 = As + 4096, *B0 = Bs, *B1 = Bs + 4096;
    STAGE(A0, B0, 0);
    __syncthreads();
    #pragma unroll 1
    for (int t = 0; t < 32; t += 2) {
        STAGE(A1, B1, t + 1);
        COMPUTE(A0, B0);
        __syncthreads();
        if (t + 2 < 32) STAGE(A0, B0, t + 2);
        COMPUTE(A1, B1);
        __syncthreads();
    }

    float bias_n[4];
    #pragma unroll
    for (int n = 0; n < 4; ++n) bias_n[n] = bias[col0 + wc * 64 + n * 16 + l16];

    if (F32OUT) {
        // scalar f32 epilogue (full-line stores; no amplification measured)
        #pragma unroll
        for (int m = 0; m < 4; ++m) {
            #pragma unroll
            for (int j = 0; j < 4; ++j) {
                int row = row0 + wr * 64 + m * 16 + lq * 4 + j;
                if (row >= NN) continue;
                #pragma unroll
                for (int n = 0; n < 4; ++n) {
                    int col = col0 + wc * 64 + n * 16 + l16;
                    size_t off = (size_t)row * HH + col;
                    float v = acc[m][n][j] + bias_n[n];
                    if (RELU) v = fmaxf(v, 0.f);
                    out[off] = v + b2f(residb[off]);
                }
            }
        }
    } else {
        // LDS-staged coalesced bf16 epilogue.
        // Logical C[rl][c] (128x128 ushort) stored at
        //   LDS[rl*128 + (((c>>3) ^ (rl&7))<<3) + (c&7)]
        #pragma unroll
        for (int m = 0; m < 4; ++m) {
            #pragma unroll
            for (int j = 0; j < 4; ++j) {
                int rl = wr * 64 + m * 16 + lq * 4 + j;
                int sx = rl & 7;
                #pragma unroll
                for (int n = 0; n < 4; ++n) {
                    int c = wc * 64 + n * 16 + l16;
                    float v = acc[m][n][j] + bias_n[n];
                    if (RELU) v = fmaxf(v, 0.f);
                    LDS[rl * 128 + ((((c >> 3) ^ sx)) << 3) + (c & 7)] = f2b(v);
                }
            }
        }
        __syncthreads();
        const int rl2 = tid >> 1;          // 0..127
        const int h   = tid & 1;           // half of the 128-col row
        const int grow = row0 + rl2;
        const bool ok = grow < NN;
        const int sx2 = rl2 & 7;
        #pragma unroll
        for (int i = 0; i < 8; ++i) {
            int g = h * 8 + i;             // 16B group index 0..15
            ushort8 cv = *(const ushort8*)&LDS[rl2 * 128 + ((g ^ sx2) << 3)];
            if (ok) {
                size_t off = (size_t)grow * HH + col0 + (g << 3);
                ushort8 rv = *(const ushort8*)&residb[off];
                ushort8 ov;
                #pragma unroll
                for (int k = 0; k < 8; ++k)
                    ov[k] = f2b(b2f(cv[k]) + b2f(rv[k]));
                *(ushort8*)&outb[off] = ov;
            }
        }
    }
}

extern "C" void kernel_launch(void* const* d_in, const int* in_sizes, int n_in,
                              void* d_out, int out_size, void* d_ws, size_t ws_size,
                              hipStream_t stream) {
    const float* x   = (const float*)d_in[0];
    const int*   ei  = (const int*)d_in[1];
    const int*   src = ei;
    const int*   dst = ei + EE;
    const float* w_rel1  = (const float*)d_in[2];
    const float* b_rel1  = (const float*)d_in[3];
    const float* w_root1 = (const float*)d_in[4];
    const float* w_rel2  = (const float*)d_in[5];
    const float* b_rel2  = (const float*)d_in[6];
    const float* w_root2 = (const float*)d_in[7];
    const float* w_rel3  = (const float*)d_in[8];
    const float* b_rel3  = (const float*)d_in[9];
    const float* w_root3 = (const float*)d_in[10];
    const float* w_rel4  = (const float*)d_in[11];
    const float* b_rel4  = (const float*)d_in[12];
    const float* w_root4 = (const float*)d_in[13];

    const size_t NH = (size_t)NN * HH;
    unsigned short* XB   = (unsigned short*)d_ws;        // x1 bf16
    unsigned short* XB2  = XB + NH;                      // x2 bf16
    unsigned short* X3B  = XB2 + NH;                     // x3 bf16
    unsigned short* AGB  = X3B + NH;                     // agg bf16
    unsigned short* WT   = AGB + NH;                     // 6 transposed bf16 weights
    float*          agg0 = (float*)(WT + 6 * 262144);
    int*            csr  = (int*)(agg0 + NN);
    int* deg       = csr;
    int* start     = csr + NN;
    int* cursor    = start + NN + 1;
    int* eidx      = cursor + NN;
    int* blockSums = eidx + EE;
    float* out = (float*)d_out;

    unsigned short* WrT2 = WT;
    unsigned short* WoT2 = WT + 1 * 262144;
    unsigned short* WrT3 = WT + 2 * 262144;
    unsigned short* WoT3 = WT + 3 * 262144;
    unsigned short* WrT4 = WT + 4 * 262144;
    unsigned short* WoT4 = WT + 5 * 262144;

    const int gGemm = 3128;  // 782 m-tiles x 4 n-tiles (128x128), XCD-chunked in-kernel

    // ---- CSR build ----
    hipMemsetAsync(deg, 0, NN * sizeof(int), stream);
    histo_deg<<<(EE + 255) / 256, 256, 0, stream>>>(dst, deg);
    scan_reduce<<<NB_SCAN, 256, 0, stream>>>(deg, blockSums);
    scan_top<<<1, 128, 0, stream>>>(blockSums, start);
    scan_down<<<NB_SCAN, 256, 0, stream>>>(deg, blockSums, start, cursor);
    csr_fill<<<(EE + 255) / 256, 256, 0, stream>>>(src, dst, cursor, eidx);

    // ---- Weights -> transposed bf16 ----
    w_transpose<<<1024, 256, 0, stream>>>(w_rel2,  WrT2);
    w_transpose<<<1024, 256, 0, stream>>>(w_root2, WoT2);
    w_transpose<<<1024, 256, 0, stream>>>(w_rel3,  WrT3);
    w_transpose<<<1024, 256, 0, stream>>>(w_root3, WoT3);
    w_transpose<<<1024, 256, 0, stream>>>(w_rel4,  WrT4);
    w_transpose<<<1024, 256, 0, stream>>>(w_root4, WoT4);

    // ---- Layer 1: x1 -> XB (bf16) ----
    gather_scalar<<<(NN + 255) / 256, 256, 0, stream>>>(x, start, eidx, agg0);
    layer1_expand<<<50000, 256, 0, stream>>>(x, agg0, w_rel1, b_rel1, w_root1, XB);

    // ---- Layer 2: x2 = relu(conv(x1)) + x1 -> XB2 (bf16) ----
    gather_rows_b<<<25000, 256, 0, stream>>>(XB, start, eidx, AGB);
    gemm_mfma<true, false><<<gGemm, 256, 0, stream>>>(
        AGB, XB, WrT2, WoT2, b_rel2, XB, nullptr, XB2);

    // ---- Layer 3: x3 = conv(x2) + x2 -> X3B (bf16) ----
    gather_rows_b<<<25000, 256, 0, stream>>>(XB2, start, eidx, AGB);
    gemm_mfma<false, false><<<gGemm, 256, 0, stream>>>(
        AGB, XB2, WrT3, WoT3, b_rel3, XB2, nullptr, X3B);

    // ---- Layer 4: x4 = conv(x3) + x3 -> d_out (f32) ----
    gather_rows_b<<<25000, 256, 0, stream>>>(X3B, start, eidx, AGB);
    gemm_mfma<false, true><<<gGemm, 256, 0, stream>>>(
        AGB, X3B, WrT4, WoT4, b_rel4, X3B, out, nullptr);
}